// Round 1
// 493.946 us; speedup vs baseline: 1.1507x; 1.1507x over previous
//
#include <hip/hip_runtime.h>

typedef __bf16 bf16_t;
typedef __bf16 bf16x8 __attribute__((ext_vector_type(8)));
typedef __bf16 bf16x4 __attribute__((ext_vector_type(4)));
typedef float f32x4 __attribute__((ext_vector_type(4)));

constexpr int TDIM = 8192;
constexpr int KDIM = 4096;
constexpr int ODIM = 4096;

// Async global->LDS, 16B per lane. LDS dest is wave-uniform base + lane*16 (fixed);
// the per-lane global SOURCE address carries the bank swizzle.
__device__ __forceinline__ void async_ld16(void* lds, const void* g) {
    __builtin_amdgcn_global_load_lds(
        (const __attribute__((address_space(1))) unsigned int*)g,
        (__attribute__((address_space(3))) unsigned int*)lds,
        16, 0, 0);
}

// fp32 -> bf16 for BOTH tensors in one launch. Fully lane-dense.
__global__ __launch_bounds__(256) void cvt2_kernel(const float* __restrict__ a, bf16_t* __restrict__ da,
                                                   int nblk_a,
                                                   const float* __restrict__ w, bf16_t* __restrict__ dw) {
    int b = blockIdx.x;
    const float* src;
    bf16_t* dst;
    if (b < nblk_a) { src = a; dst = da; }
    else            { src = w; dst = dw; b -= nblk_a; }
    const size_t base = (size_t)b * 2048 + threadIdx.x * 4;
    const float4 v0 = *(const float4*)(src + base);
    const float4 v1 = *(const float4*)(src + base + 1024);
    bf16x4 o0, o1;
    o0[0] = (bf16_t)v0.x; o0[1] = (bf16_t)v0.y; o0[2] = (bf16_t)v0.z; o0[3] = (bf16_t)v0.w;
    o1[0] = (bf16_t)v1.x; o1[1] = (bf16_t)v1.y; o1[2] = (bf16_t)v1.z; o1[3] = (bf16_t)v1.w;
    *(bf16x4*)(dst + base) = o0;
    *(bf16x4*)(dst + base + 1024) = o1;
}

// ---------------------------------------------------------------------------
// 256x256 8-phase GEMM (T1+T2+T3+T4+T5), BK=64, 8 waves (2Mx4N), LDS 128 KiB.
// C[t,o] = sum_k A[t,k]*B[o,k]; fused dequant epilogue.
//
// LDS map (bytes): A buf c @ c*32768, B buf c @ 65536 + c*32768.
// Within a tile: row r (0..255) at r*128; logical k-chunk c (16B, k=c*8..c*8+7)
// stored at physical chunk c ^ (r&7)  -> ds_read_b128 start banks spread over
// 8 distinct 16B slots per 16-lane group => 2-way max (free, m136).
// global_load_lds writes linearly (thread t -> row t>>3, phys chunk t&7), so
// thread t FETCHES logical chunk (t&7) ^ ((t>>3)&7)  (inverse == same XOR).
//
// Phase schedule per iteration (2 K-tiles: t0=2i -> buf0, t1=2i+1 -> buf1):
//  P1: rd buf0{A m0-3,B all}; stage buf1.A1(t1)   | mfma m0-3 x n0-1
//  P2:                        stage buf0.B0(t0+2) | mfma m0-3 x n2-3
//  P3: rd buf0{A m4-7};       stage buf0.B1(t0+2) | mfma m4-7 x n0-1
//  P4:                        stage buf0.A0(t0+2) | mfma m4-7 x n2-3 ; vmcnt(6)
//  P5: rd buf1{A m0-3,B all}; stage buf0.A1(t0+2) | mfma m0-3 x n0-1
//  P6:                        stage buf1.B0(t1+2) | mfma m0-3 x n2-3
//  P7: rd buf1{A m4-7};       stage buf1.B1(t1+2) | mfma m4-7 x n0-1
//  P8:                        stage buf1.A0(t1+2) | mfma m4-7 x n2-3 ; vmcnt(6)
// Reads of a region always finish >=1 phase (barrier) before it is re-staged;
// at each vmcnt(6) the 6 outstanding loads are exactly the NEXT 3 half-tiles,
// so the tile about to be consumed is fully landed. Last iter drains vmcnt(0).
// ---------------------------------------------------------------------------
constexpr int BM = 256, BN = 256, BK = 64;
constexpr int NKT = KDIM / BK;   // 64 K-tiles
constexpr int NIT = NKT / 2;     // 32 iterations

#define BAR   __builtin_amdgcn_s_barrier()
#define SCB   __builtin_amdgcn_sched_barrier(0)
#define WLG   asm volatile("s_waitcnt lgkmcnt(0)" ::: "memory")
#define WV6   asm volatile("s_waitcnt vmcnt(6)" ::: "memory")
#define WV0   asm volatile("s_waitcnt vmcnt(0)" ::: "memory")
#define PRIO1 __builtin_amdgcn_s_setprio(1)
#define PRIO0 __builtin_amdgcn_s_setprio(0)

// Stage one half-tile (128 rows x 64 k) = 2 global_load_lds per thread.
#define STG_A(c, kt, h) \
    async_ld16(lds_a + (c)*32768 + (h)*16384,        a_srcb + (size_t)((h)*128     )*KDIM + (kt)*64); \
    async_ld16(lds_a + (c)*32768 + (h)*16384 + 8192, a_srcb + (size_t)((h)*128 + 64)*KDIM + (kt)*64)
#define STG_B(c, kt, h) \
    async_ld16(lds_b + (c)*32768 + (h)*16384,        b_srcb + (size_t)((h)*128     )*KDIM + (kt)*64); \
    async_ld16(lds_b + (c)*32768 + (h)*16384 + 8192, b_srcb + (size_t)((h)*128 + 64)*KDIM + (kt)*64)

#define LD_A_LO(c) _Pragma("unroll") for (int m = 0; m < 4; ++m) { \
    af[m][0] = *(const bf16x8*)(a_rd + (c)*32768 + m*2048 + ck0); \
    af[m][1] = *(const bf16x8*)(a_rd + (c)*32768 + m*2048 + ck1); }
#define LD_A_HI(c) _Pragma("unroll") for (int m = 0; m < 4; ++m) { \
    af[m][0] = *(const bf16x8*)(a_rd + (c)*32768 + (m+4)*2048 + ck0); \
    af[m][1] = *(const bf16x8*)(a_rd + (c)*32768 + (m+4)*2048 + ck1); }
#define LD_B_ALL(c) _Pragma("unroll") for (int n = 0; n < 4; ++n) { \
    bfr[n][0] = *(const bf16x8*)(b_rd + (c)*32768 + n*2048 + ck0); \
    bfr[n][1] = *(const bf16x8*)(b_rd + (c)*32768 + n*2048 + ck1); }

#define MFMA16(MB, NB) \
  _Pragma("unroll") for (int m = 0; m < 4; ++m) \
  _Pragma("unroll") for (int n = 0; n < 2; ++n) \
  _Pragma("unroll") for (int k = 0; k < 2; ++k) \
    acc[(MB)+m][(NB)+n] = __builtin_amdgcn_mfma_f32_16x16x32_bf16( \
        af[m][k], bfr[(NB)+n][k], acc[(MB)+m][(NB)+n], 0, 0, 0)

__global__ __launch_bounds__(512, 2) void gemm8_kernel(
    const bf16_t* __restrict__ A, const bf16_t* __restrict__ B,
    const float* __restrict__ scale_x, const float* __restrict__ scale_w,
    const float* __restrict__ gscale, const float* __restrict__ bias,
    float* __restrict__ out)
{
    __shared__ __attribute__((aligned(16))) char smem[131072];

    const int tid = threadIdx.x;
    // T1: bijective XCD swizzle (512 % 8 == 0); bn fast within an XCD so its
    // 64 blocks share a 2 MB A-panel in the XCD-private L2.
    const int lin = (blockIdx.x & 7) * 64 + (blockIdx.x >> 3);
    const int row0 = (lin >> 4) * BM;   // 32 M-tiles (t)
    const int col0 = (lin & 15) * BN;   // 16 N-tiles (o)

    // staging map: thread t -> LDS slot (row t>>3, phys chunk t&7) per 64-row line
    const int ld_row = tid >> 3;
    const int ld_ch  = (tid & 7) ^ (ld_row & 7);   // logical chunk to fetch
    const bf16_t* a_srcb = A + (size_t)(row0 + ld_row) * KDIM + ld_ch * 8;
    const bf16_t* b_srcb = B + (size_t)(col0 + ld_row) * KDIM + ld_ch * 8;
    char* lds_a = smem + tid * 16;
    char* lds_b = smem + 65536 + tid * 16;

    // fragment read map
    const int lane = tid & 63;
    const int wid  = tid >> 6;
    const int wm   = wid >> 2;          // 0..1  (128-row slab)
    const int wn   = wid & 3;           // 0..3  (64-col slab)
    const int fr   = lane & 15;
    const int q    = lane >> 4;         // k-quad
    const int swz  = lane & 7;          // == (frag row)&7 for all mt/nt
    const int ck0  = ((q ^ swz)) * 16;        // ks=0 physical chunk byte
    const int ck1  = (((4 | q) ^ swz)) * 16;  // ks=1
    const char* a_rd = smem + (wm * 128 + fr) * 128;
    const char* b_rd = smem + 65536 + (wn * 64 + fr) * 128;

    f32x4 acc[8][4] = {};
    bf16x8 af[4][2], bfr[4][2];

    // Prologue: tile0 {B0,B1,A0,A1} -> buf0, tile1 {B0,B1,A0} -> buf1 (14 loads),
    // wait tile0 landed (6 left outstanding = steady state), barrier.
    STG_B(0, 0, 0); STG_B(0, 0, 1);
    STG_A(0, 0, 0); STG_A(0, 0, 1);
    STG_B(1, 1, 0); STG_B(1, 1, 1);
    STG_A(1, 1, 0);
    WV6; SCB; BAR; SCB;

#pragma unroll 1
    for (int i = 0; i < NIT; ++i) {
        const int tp = 2 * i + 2;          // prefetch K-tile pair base
        const bool pf = (tp < NKT);
        // ---- P1 ----
        LD_A_LO(0); LD_B_ALL(0);
        STG_A(1, 2 * i + 1, 1);
        BAR; WLG; SCB;
        PRIO1; MFMA16(0, 0); PRIO0; SCB; BAR; SCB;
        // ---- P2 ----
        if (pf) { STG_B(0, tp, 0); }
        BAR; SCB;
        PRIO1; MFMA16(0, 2); PRIO0; SCB; BAR; SCB;
        // ---- P3 ----
        LD_A_HI(0);
        if (pf) { STG_B(0, tp, 1); }
        BAR; WLG; SCB;
        PRIO1; MFMA16(4, 0); PRIO0; SCB; BAR; SCB;
        // ---- P4 ----
        if (pf) { STG_A(0, tp, 0); }
        BAR; SCB;
        PRIO1; MFMA16(4, 2); PRIO0; SCB;
        if (i + 1 < NIT) { WV6; } else { WV0; }
        SCB; BAR; SCB;
        // ---- P5 ----
        LD_A_LO(1); LD_B_ALL(1);
        if (pf) { STG_A(0, tp, 1); }
        BAR; WLG; SCB;
        PRIO1; MFMA16(0, 0); PRIO0; SCB; BAR; SCB;
        // ---- P6 ----
        if (pf) { STG_B(1, tp + 1, 0); }
        BAR; SCB;
        PRIO1; MFMA16(0, 2); PRIO0; SCB; BAR; SCB;
        // ---- P7 ----
        LD_A_HI(1);
        if (pf) { STG_B(1, tp + 1, 1); }
        BAR; WLG; SCB;
        PRIO1; MFMA16(4, 0); PRIO0; SCB; BAR; SCB;
        // ---- P8 ----
        if (pf) { STG_A(1, tp + 1, 0); }
        BAR; SCB;
        PRIO1; MFMA16(4, 2); PRIO0; SCB;
        WV6; SCB; BAR; SCB;
    }

    // Epilogue: C/D layout col=lane&15, row=(lane>>4)*4+reg [m89/m91-verified]
    const float gs = gscale[0];
    const int trow = row0 + wm * 128 + q * 4;
    const int ocol = col0 + wn * 64 + fr;
#pragma unroll
    for (int nt = 0; nt < 4; ++nt) {
        const int o = ocol + nt * 16;
        const float sws = scale_w[o] * gs;
        const float bv = bias[o];
#pragma unroll
        for (int mt = 0; mt < 8; ++mt) {
#pragma unroll
            for (int ii = 0; ii < 4; ++ii) {
                const int t = trow + mt * 16 + ii;
                out[(size_t)t * ODIM + o] = acc[mt][nt][ii] * (scale_x[t] * sws) + bv;
            }
        }
    }
}

// ---------------------------------------------------------------------------
// Fallback (no workspace): previous verified 128x128 kernel, fp32-load path.
// ---------------------------------------------------------------------------
constexpr int FBM = 128, FBN = 128, FBK = 32;

__global__ __launch_bounds__(256, 4) void gemm_fallback(
    const float* __restrict__ Afp, const float* __restrict__ Bfp,
    const float* __restrict__ scale_x, const float* __restrict__ scale_w,
    const float* __restrict__ gscale, const float* __restrict__ bias,
    float* __restrict__ out) {
    __shared__ bf16_t sA[FBM * FBK];
    __shared__ bf16_t sB[FBN * FBK];

    const int tid = threadIdx.x;
    const int bn = blockIdx.x & 31;
    const int bm = blockIdx.x >> 5;
    const int row0 = bm * FBM;
    const int col0 = bn * FBN;

    const int lane = tid & 63;
    const int wid = tid >> 6;
    const int wm = (wid >> 1) * 64;
    const int wn = (wid & 1) * 64;
    const int fr = lane & 15;
    const int q  = lane >> 4;
    const int s_fr = (fr >> 1) & 3;
    const int kc = ((q ^ s_fr) * 8);

    f32x4 acc[4][4] = {};

    for (int k0 = 0; k0 < KDIM; k0 += FBK) {
        const int r = tid >> 2;
        const int cg2 = (tid & 3) ^ ((tid >> 3) & 3);
#pragma unroll
        for (int h = 0; h < 2; ++h) {
            const int rr = r + h * 64;
            const float4 va0 = *(const float4*)(Afp + (size_t)(row0 + rr) * KDIM + k0 + cg2 * 8);
            const float4 va1 = *(const float4*)(Afp + (size_t)(row0 + rr) * KDIM + k0 + cg2 * 8 + 4);
            const float4 vb0 = *(const float4*)(Bfp + (size_t)(col0 + rr) * KDIM + k0 + cg2 * 8);
            const float4 vb1 = *(const float4*)(Bfp + (size_t)(col0 + rr) * KDIM + k0 + cg2 * 8 + 4);
            bf16x8 pa, pb;
            pa[0] = (bf16_t)va0.x; pa[1] = (bf16_t)va0.y; pa[2] = (bf16_t)va0.z; pa[3] = (bf16_t)va0.w;
            pa[4] = (bf16_t)va1.x; pa[5] = (bf16_t)va1.y; pa[6] = (bf16_t)va1.z; pa[7] = (bf16_t)va1.w;
            pb[0] = (bf16_t)vb0.x; pb[1] = (bf16_t)vb0.y; pb[2] = (bf16_t)vb0.z; pb[3] = (bf16_t)vb0.w;
            pb[4] = (bf16_t)vb1.x; pb[5] = (bf16_t)vb1.y; pb[6] = (bf16_t)vb1.z; pb[7] = (bf16_t)vb1.w;
            *(bf16x8*)&sA[rr * FBK + (tid & 3) * 8] = pa;
            *(bf16x8*)&sB[rr * FBK + (tid & 3) * 8] = pb;
        }
        __syncthreads();

        bf16x8 a8[4], b8[4];
#pragma unroll
        for (int mt = 0; mt < 4; ++mt)
            a8[mt] = *(const bf16x8*)&sA[(wm + mt * 16 + fr) * FBK + kc];
#pragma unroll
        for (int nt = 0; nt < 4; ++nt)
            b8[nt] = *(const bf16x8*)&sB[(wn + nt * 16 + fr) * FBK + kc];
#pragma unroll
        for (int mt = 0; mt < 4; ++mt)
#pragma unroll
            for (int nt = 0; nt < 4; ++nt)
                acc[mt][nt] = __builtin_amdgcn_mfma_f32_16x16x32_bf16(a8[mt], b8[nt], acc[mt][nt], 0, 0, 0);
        __syncthreads();
    }

    const float gs = gscale[0];
    const int rbase = q * 4;
#pragma unroll
    for (int nt = 0; nt < 4; ++nt) {
        const int o = col0 + wn + nt * 16 + fr;
        const float swv = scale_w[o] * gs;
        const float bv = bias[o];
#pragma unroll
        for (int mt = 0; mt < 4; ++mt) {
#pragma unroll
            for (int i = 0; i < 4; ++i) {
                const int t = row0 + wm + mt * 16 + rbase + i;
                out[(size_t)t * ODIM + o] = acc[mt][nt][i] * (scale_x[t] * swv) + bv;
            }
        }
    }
}

extern "C" void kernel_launch(void* const* d_in, const int* in_sizes, int n_in,
                              void* d_out, int out_size, void* d_ws, size_t ws_size,
                              hipStream_t stream) {
    const float* qx   = (const float*)d_in[0];  // (T,K)
    const float* W    = (const float*)d_in[1];  // (O,K)
    const float* sx   = (const float*)d_in[2];  // (T,1)
    const float* sw   = (const float*)d_in[3];  // (O,)
    const float* gs   = (const float*)d_in[4];  // (1,)
    const float* bias = (const float*)d_in[5];  // (O,)
    float* out = (float*)d_out;

    const size_t nA = (size_t)TDIM * KDIM;
    const size_t nW = (size_t)ODIM * KDIM;

    if (ws_size >= (nA + nW) * sizeof(bf16_t)) {
        bf16_t* Abf = (bf16_t*)d_ws;
        bf16_t* Wbf = Abf + nA;
        const int nblk_a = (int)(nA / 2048);
        const int nblk_w = (int)(nW / 2048);
        cvt2_kernel<<<dim3(nblk_a + nblk_w), dim3(256), 0, stream>>>(qx, Abf, nblk_a, W, Wbf);
        gemm8_kernel<<<dim3((TDIM / BM) * (ODIM / BN)), dim3(512), 0, stream>>>(
            Abf, Wbf, sx, sw, gs, bias, out);
    } else {
        gemm_fallback<<<dim3((TDIM / FBM) * (ODIM / FBN)), dim3(256), 0, stream>>>(
            qx, W, sx, sw, gs, bias, out);
    }
}

// Round 2
// 487.482 us; speedup vs baseline: 1.1659x; 1.0133x over previous
//
#include <hip/hip_runtime.h>

typedef __bf16 bf16_t;
typedef __bf16 bf16x8 __attribute__((ext_vector_type(8)));
typedef __bf16 bf16x4 __attribute__((ext_vector_type(4)));
typedef float f32x4 __attribute__((ext_vector_type(4)));

constexpr int TDIM = 8192;
constexpr int KDIM = 4096;
constexpr int ODIM = 4096;

// Async global->LDS, 16B per lane. LDS dest is wave-uniform base + lane*16 (fixed);
// the per-lane global SOURCE address carries the bank swizzle.
__device__ __forceinline__ void async_ld16(void* lds, const void* g) {
    __builtin_amdgcn_global_load_lds(
        (const __attribute__((address_space(1))) unsigned int*)g,
        (__attribute__((address_space(3))) unsigned int*)lds,
        16, 0, 0);
}

// fp32 -> bf16 for BOTH tensors in one launch. Fully lane-dense.
__global__ __launch_bounds__(256) void cvt2_kernel(const float* __restrict__ a, bf16_t* __restrict__ da,
                                                   int nblk_a,
                                                   const float* __restrict__ w, bf16_t* __restrict__ dw) {
    int b = blockIdx.x;
    const float* src;
    bf16_t* dst;
    if (b < nblk_a) { src = a; dst = da; }
    else            { src = w; dst = dw; b -= nblk_a; }
    const size_t base = (size_t)b * 2048 + threadIdx.x * 4;
    const float4 v0 = *(const float4*)(src + base);
    const float4 v1 = *(const float4*)(src + base + 1024);
    bf16x4 o0, o1;
    o0[0] = (bf16_t)v0.x; o0[1] = (bf16_t)v0.y; o0[2] = (bf16_t)v0.z; o0[3] = (bf16_t)v0.w;
    o1[0] = (bf16_t)v1.x; o1[1] = (bf16_t)v1.y; o1[2] = (bf16_t)v1.z; o1[3] = (bf16_t)v1.w;
    *(bf16x4*)(dst + base) = o0;
    *(bf16x4*)(dst + base + 1024) = o1;
}

// ---------------------------------------------------------------------------
// 256x256 8-phase GEMM with READ-AHEAD (T1+T2+T3+T4+T5 + LDS->reg pipelining).
// BK=64, 8 waves (2Mx4N), LDS 128 KiB double-buffered across K-tile pairs.
//
// Phase body: [W: stage (+vmcnt at P4/P8)] BAR; lgkm(0); MFMA; ra-reads(next); BAR
// ds_reads for phase N's MFMA are issued at the END of phase N-1 -> they drain
// across the end-barrier + next stage window instead of stalling the MFMA.
//
// RAW: vmcnt(6) sits in the P4/P8 stage window BEFORE the pre-MFMA barrier, so
// the barrier certifies block-wide landing of loads through P1 (resp. P5);
// the ra-reads of the fresh buffer issue after that barrier.
// WAR: every ra-read's data is consumed (lgkm(0)) >=1 barrier before the stage
// that overwrites its region (checked per phase/half/tensor).
// Frag liveness: B23 regs free during P1/P5, af overwritable after P2/P6,
// all frags free after P4/P8 -> no extra registers needed.
// ---------------------------------------------------------------------------
constexpr int BM = 256, BN = 256, BK = 64;
constexpr int NKT = KDIM / BK;   // 64 K-tiles
constexpr int NIT = NKT / 2;     // 32 iterations

#define BAR   __builtin_amdgcn_s_barrier()
#define SCB   __builtin_amdgcn_sched_barrier(0)
#define WLG   asm volatile("s_waitcnt lgkmcnt(0)" ::: "memory")
#define WV6   asm volatile("s_waitcnt vmcnt(6)" ::: "memory")
#define WV0   asm volatile("s_waitcnt vmcnt(0)" ::: "memory")
#define PRIO1 __builtin_amdgcn_s_setprio(1)
#define PRIO0 __builtin_amdgcn_s_setprio(0)

// Stage one half-tile (128 rows x 64 k) = 2 global_load_lds per thread.
#define STG_A(c, kt, h) \
    async_ld16(lds_a + (c)*32768 + (h)*16384,        a_srcb + (size_t)((h)*128     )*KDIM + (kt)*64); \
    async_ld16(lds_a + (c)*32768 + (h)*16384 + 8192, a_srcb + (size_t)((h)*128 + 64)*KDIM + (kt)*64)
#define STG_B(c, kt, h) \
    async_ld16(lds_b + (c)*32768 + (h)*16384,        b_srcb + (size_t)((h)*128     )*KDIM + (kt)*64); \
    async_ld16(lds_b + (c)*32768 + (h)*16384 + 8192, b_srcb + (size_t)((h)*128 + 64)*KDIM + (kt)*64)

#define LD_A_LO(c) _Pragma("unroll") for (int m = 0; m < 4; ++m) { \
    af[m][0] = *(const bf16x8*)(a_rd + (c)*32768 + m*2048 + ck0); \
    af[m][1] = *(const bf16x8*)(a_rd + (c)*32768 + m*2048 + ck1); }
#define LD_A_HI(c) _Pragma("unroll") for (int m = 0; m < 4; ++m) { \
    af[m][0] = *(const bf16x8*)(a_rd + (c)*32768 + (m+4)*2048 + ck0); \
    af[m][1] = *(const bf16x8*)(a_rd + (c)*32768 + (m+4)*2048 + ck1); }
#define LD_B01(c) _Pragma("unroll") for (int n = 0; n < 2; ++n) { \
    bfr[n][0] = *(const bf16x8*)(b_rd + (c)*32768 + n*2048 + ck0); \
    bfr[n][1] = *(const bf16x8*)(b_rd + (c)*32768 + n*2048 + ck1); }
#define LD_B23(c) _Pragma("unroll") for (int n = 2; n < 4; ++n) { \
    bfr[n][0] = *(const bf16x8*)(b_rd + (c)*32768 + n*2048 + ck0); \
    bfr[n][1] = *(const bf16x8*)(b_rd + (c)*32768 + n*2048 + ck1); }

#define MFMA16(MB, NB) \
  _Pragma("unroll") for (int m = 0; m < 4; ++m) \
  _Pragma("unroll") for (int n = 0; n < 2; ++n) \
  _Pragma("unroll") for (int k = 0; k < 2; ++k) \
    acc[(MB)+m][(NB)+n] = __builtin_amdgcn_mfma_f32_16x16x32_bf16( \
        af[m][k], bfr[(NB)+n][k], acc[(MB)+m][(NB)+n], 0, 0, 0)

__global__ __launch_bounds__(512, 2) void gemm8_kernel(
    const bf16_t* __restrict__ A, const bf16_t* __restrict__ B,
    const float* __restrict__ scale_x, const float* __restrict__ scale_w,
    const float* __restrict__ gscale, const float* __restrict__ bias,
    float* __restrict__ out)
{
    __shared__ __attribute__((aligned(16))) char smem[131072];

    const int tid = threadIdx.x;
    // T1: bijective XCD swizzle (512 % 8 == 0); bn fast within an XCD.
    const int lin = (blockIdx.x & 7) * 64 + (blockIdx.x >> 3);
    const int row0 = (lin >> 4) * BM;   // 32 M-tiles (t)
    const int col0 = (lin & 15) * BN;   // 16 N-tiles (o)

    // staging map: thread t -> LDS slot (row t>>3, phys chunk t&7) per 64-row line
    const int ld_row = tid >> 3;
    const int ld_ch  = (tid & 7) ^ (ld_row & 7);   // logical chunk to fetch
    const bf16_t* a_srcb = A + (size_t)(row0 + ld_row) * KDIM + ld_ch * 8;
    const bf16_t* b_srcb = B + (size_t)(col0 + ld_row) * KDIM + ld_ch * 8;
    char* lds_a = smem + tid * 16;
    char* lds_b = smem + 65536 + tid * 16;

    // fragment read map
    const int lane = tid & 63;
    const int wid  = tid >> 6;
    const int wm   = wid >> 2;          // 0..1  (128-row slab)
    const int wn   = wid & 3;           // 0..3  (64-col slab)
    const int fr   = lane & 15;
    const int q    = lane >> 4;         // k-quad
    const int swz  = lane & 7;          // == (frag row)&7 for all mt/nt
    const int ck0  = ((q ^ swz)) * 16;        // ks=0 physical chunk byte
    const int ck1  = (((4 | q) ^ swz)) * 16;  // ks=1
    const char* a_rd = smem + (wm * 128 + fr) * 128;
    const char* b_rd = smem + 65536 + (wn * 64 + fr) * 128;

    f32x4 acc[8][4] = {};
    bf16x8 af[4][2], bfr[4][2];

    // Prologue: tile0 -> buf0 (8 loads), tile1 {B0,B1,A0} -> buf1 (6 loads).
    // vmcnt(6): own tile0 landed; BAR certifies block-wide; then read-ahead P1.
    STG_B(0, 0, 0); STG_B(0, 0, 1);
    STG_A(0, 0, 0); STG_A(0, 0, 1);
    STG_B(1, 1, 0); STG_B(1, 1, 1);
    STG_A(1, 1, 0);
    WV6; SCB; BAR; SCB;
    LD_A_LO(0); LD_B01(0); SCB;

#pragma unroll 1
    for (int i = 0; i < NIT; ++i) {
        const int tp = 2 * i + 2;          // prefetch K-tile pair base
        const bool pf = (tp < NKT);
        const bool last = (i + 1 == NIT);
        // ---- P1 : MFMA LOx01(buf0) ----
        STG_A(1, 2 * i + 1, 1);
        BAR; WLG; SCB;
        PRIO1; MFMA16(0, 0); PRIO0; SCB;
        LD_B23(0); SCB; BAR; SCB;
        // ---- P2 : MFMA LOx23(buf0) ----
        if (pf) { STG_B(0, tp, 0); }
        BAR; WLG; SCB;
        PRIO1; MFMA16(0, 2); PRIO0; SCB;
        LD_A_HI(0); SCB; BAR; SCB;
        // ---- P3 : MFMA HIx01(buf0) ----
        if (pf) { STG_B(0, tp, 1); }
        BAR; WLG; SCB;
        PRIO1; MFMA16(4, 0); PRIO0; SCB; BAR; SCB;
        // ---- P4 : MFMA HIx23(buf0); vmcnt certifies buf1 tile 2i+1 ----
        if (pf) { STG_A(0, tp, 0); }
        if (!last) { WV6; } else { WV0; }
        SCB; BAR; SCB;
        PRIO1; MFMA16(4, 2); PRIO0; SCB;
        LD_A_LO(1); LD_B01(1); SCB; BAR; SCB;
        // ---- P5 : MFMA LOx01(buf1) ----
        if (pf) { STG_A(0, tp, 1); }
        BAR; WLG; SCB;
        PRIO1; MFMA16(0, 0); PRIO0; SCB;
        LD_B23(1); SCB; BAR; SCB;
        // ---- P6 : MFMA LOx23(buf1) ----
        if (pf) { STG_B(1, tp + 1, 0); }
        BAR; WLG; SCB;
        PRIO1; MFMA16(0, 2); PRIO0; SCB;
        LD_A_HI(1); SCB; BAR; SCB;
        // ---- P7 : MFMA HIx01(buf1) ----
        if (pf) { STG_B(1, tp + 1, 1); }
        BAR; WLG; SCB;
        PRIO1; MFMA16(4, 0); PRIO0; SCB; BAR; SCB;
        // ---- P8 : MFMA HIx23(buf1); vmcnt certifies buf0 tile tp ----
        if (pf) { STG_A(1, tp + 1, 0); }
        WV6; SCB; BAR; SCB;
        PRIO1; MFMA16(4, 2); PRIO0; SCB;
        if (!last) { LD_A_LO(0); LD_B01(0); }
        SCB; BAR; SCB;
    }

    // Epilogue: C/D layout col=lane&15, row=(lane>>4)*4+reg [m89/m91-verified]
    const float gs = gscale[0];
    const int trow = row0 + wm * 128 + q * 4;
    const int ocol = col0 + wn * 64 + fr;
#pragma unroll
    for (int nt = 0; nt < 4; ++nt) {
        const int o = ocol + nt * 16;
        const float sws = scale_w[o] * gs;
        const float bv = bias[o];
#pragma unroll
        for (int mt = 0; mt < 8; ++mt) {
#pragma unroll
            for (int ii = 0; ii < 4; ++ii) {
                const int t = trow + mt * 16 + ii;
                out[(size_t)t * ODIM + o] = acc[mt][nt][ii] * (scale_x[t] * sws) + bv;
            }
        }
    }
}

// ---------------------------------------------------------------------------
// Fallback (no workspace): previous verified 128x128 kernel, fp32-load path.
// ---------------------------------------------------------------------------
constexpr int FBM = 128, FBN = 128, FBK = 32;

__global__ __launch_bounds__(256, 4) void gemm_fallback(
    const float* __restrict__ Afp, const float* __restrict__ Bfp,
    const float* __restrict__ scale_x, const float* __restrict__ scale_w,
    const float* __restrict__ gscale, const float* __restrict__ bias,
    float* __restrict__ out) {
    __shared__ bf16_t sA[FBM * FBK];
    __shared__ bf16_t sB[FBN * FBK];

    const int tid = threadIdx.x;
    const int bn = blockIdx.x & 31;
    const int bm = blockIdx.x >> 5;
    const int row0 = bm * FBM;
    const int col0 = bn * FBN;

    const int lane = tid & 63;
    const int wid = tid >> 6;
    const int wm = (wid >> 1) * 64;
    const int wn = (wid & 1) * 64;
    const int fr = lane & 15;
    const int q  = lane >> 4;
    const int s_fr = (fr >> 1) & 3;
    const int kc = ((q ^ s_fr) * 8);

    f32x4 acc[4][4] = {};

    for (int k0 = 0; k0 < KDIM; k0 += FBK) {
        const int r = tid >> 2;
        const int cg2 = (tid & 3) ^ ((tid >> 3) & 3);
#pragma unroll
        for (int h = 0; h < 2; ++h) {
            const int rr = r + h * 64;
            const float4 va0 = *(const float4*)(Afp + (size_t)(row0 + rr) * KDIM + k0 + cg2 * 8);
            const float4 va1 = *(const float4*)(Afp + (size_t)(row0 + rr) * KDIM + k0 + cg2 * 8 + 4);
            const float4 vb0 = *(const float4*)(Bfp + (size_t)(col0 + rr) * KDIM + k0 + cg2 * 8);
            const float4 vb1 = *(const float4*)(Bfp + (size_t)(col0 + rr) * KDIM + k0 + cg2 * 8 + 4);
            bf16x8 pa, pb;
            pa[0] = (bf16_t)va0.x; pa[1] = (bf16_t)va0.y; pa[2] = (bf16_t)va0.z; pa[3] = (bf16_t)va0.w;
            pa[4] = (bf16_t)va1.x; pa[5] = (bf16_t)va1.y; pa[6] = (bf16_t)va1.z; pa[7] = (bf16_t)va1.w;
            pb[0] = (bf16_t)vb0.x; pb[1] = (bf16_t)vb0.y; pb[2] = (bf16_t)vb0.z; pb[3] = (bf16_t)vb0.w;
            pb[4] = (bf16_t)vb1.x; pb[5] = (bf16_t)vb1.y; pb[6] = (bf16_t)vb1.z; pb[7] = (bf16_t)vb1.w;
            *(bf16x8*)&sA[rr * FBK + (tid & 3) * 8] = pa;
            *(bf16x8*)&sB[rr * FBK + (tid & 3) * 8] = pb;
        }
        __syncthreads();

        bf16x8 a8[4], b8[4];
#pragma unroll
        for (int mt = 0; mt < 4; ++mt)
            a8[mt] = *(const bf16x8*)&sA[(wm + mt * 16 + fr) * FBK + kc];
#pragma unroll
        for (int nt = 0; nt < 4; ++nt)
            b8[nt] = *(const bf16x8*)&sB[(wn + nt * 16 + fr) * FBK + kc];
#pragma unroll
        for (int mt = 0; mt < 4; ++mt)
#pragma unroll
            for (int nt = 0; nt < 4; ++nt)
                acc[mt][nt] = __builtin_amdgcn_mfma_f32_16x16x32_bf16(a8[mt], b8[nt], acc[mt][nt], 0, 0, 0);
        __syncthreads();
    }

    const float gs = gscale[0];
    const int rbase = q * 4;
#pragma unroll
    for (int nt = 0; nt < 4; ++nt) {
        const int o = col0 + wn + nt * 16 + fr;
        const float swv = scale_w[o] * gs;
        const float bv = bias[o];
#pragma unroll
        for (int mt = 0; mt < 4; ++mt) {
#pragma unroll
            for (int i = 0; i < 4; ++i) {
                const int t = row0 + wm + mt * 16 + rbase + i;
                out[(size_t)t * ODIM + o] = acc[mt][nt][i] * (scale_x[t] * swv) + bv;
            }
        }
    }
}

extern "C" void kernel_launch(void* const* d_in, const int* in_sizes, int n_in,
                              void* d_out, int out_size, void* d_ws, size_t ws_size,
                              hipStream_t stream) {
    const float* qx   = (const float*)d_in[0];  // (T,K)
    const float* W    = (const float*)d_in[1];  // (O,K)
    const float* sx   = (const float*)d_in[2];  // (T,1)
    const float* sw   = (const float*)d_in[3];  // (O,)
    const float* gs   = (const float*)d_in[4];  // (1,)
    const float* bias = (const float*)d_in[5];  // (O,)
    float* out = (float*)d_out;

    const size_t nA = (size_t)TDIM * KDIM;
    const size_t nW = (size_t)ODIM * KDIM;

    if (ws_size >= (nA + nW) * sizeof(bf16_t)) {
        bf16_t* Abf = (bf16_t*)d_ws;
        bf16_t* Wbf = Abf + nA;
        const int nblk_a = (int)(nA / 2048);
        const int nblk_w = (int)(nW / 2048);
        cvt2_kernel<<<dim3(nblk_a + nblk_w), dim3(256), 0, stream>>>(qx, Abf, nblk_a, W, Wbf);
        gemm8_kernel<<<dim3((TDIM / BM) * (ODIM / BN)), dim3(512), 0, stream>>>(
            Abf, Wbf, sx, sw, gs, bias, out);
    } else {
        gemm_fallback<<<dim3((TDIM / FBM) * (ODIM / FBN)), dim3(256), 0, stream>>>(
            qx, W, sx, sw, gs, bias, out);
    }
}